// Round 3
// baseline (201.653 us; speedup 1.0000x reference)
//
#include <hip/hip_runtime.h>

#define BINS 128
#define FEAT 64
#define SEG (BINS * FEAT)     // 8192 counters per (b,chunk) partial
#define B_DIM 32
#define S_DIM 16384
#define CHUNKS 32             // S-chunks per batch -> 1024 blocks
#define THREADS 512           // 8 waves
#define UNROLL 8
#define ROWS_PER_BLOCK (S_DIM / CHUNKS)                // 512
#define ROWS_PER_WAVE  (ROWS_PER_BLOCK / (THREADS/64)) // 64

// ---------- main path: private partials in d_ws, no global atomics ----------

// grid = (CHUNKS, B_DIM), block = THREADS.
// Each block builds an LDS uint histogram over its S-chunk, then stores it
// as a private partial into d_ws with plain coalesced dwordx4 stores.
__global__ __launch_bounds__(THREADS, 8)   // 4 blocks/CU (32 waves), LDS 4x32K=128K
void hist_kernel(const float* __restrict__ x, unsigned* __restrict__ part) {
    __shared__ unsigned hist[SEG];
    for (int i = threadIdx.x; i < SEG; i += THREADS) hist[i] = 0u;
    __syncthreads();

    const int c    = blockIdx.x;
    const int b    = blockIdx.y;
    const int lane = threadIdx.x & 63;
    const int wave = threadIdx.x >> 6;               // 0..7

    const float* xb = x + ((size_t)b * S_DIM
                           + (size_t)c * ROWS_PER_BLOCK
                           + wave * ROWS_PER_WAVE) * FEAT;

    for (int it = 0; it < ROWS_PER_WAVE; it += UNROLL) {
        float v[UNROLL];
        #pragma unroll
        for (int u = 0; u < UNROLL; ++u)
            v[u] = xb[(it + u) * FEAT + lane];       // coalesced 256B/wave/load
        #pragma unroll
        for (int u = 0; u < UNROLL; ++u) {
            int bin = (int)(v[u] * 128.0f);          // exact: x*2^7, trunc like ref
            bin = bin < 0 ? 0 : (bin > 127 ? 127 : bin);
            // addr = bin*64 + lane: distinct per lane, bank = lane%32 (free 2-way)
            atomicAdd(&hist[(bin << 6) + lane], 1u); // ds_add_u32 (8 waves share LDS)
        }
    }
    __syncthreads();

    // Store private partial: coalesced uint4 stores, no atomics.
    unsigned* p = part + ((size_t)b * CHUNKS + c) * SEG;
    for (int i = threadIdx.x * 4; i < SEG; i += THREADS * 4) {
        uint4 v4 = *(const uint4*)&hist[i];          // ds_read_b128
        *(uint4*)&p[i] = v4;                         // global_store_dwordx4
    }
}

// out[b][bin][f] = weights[bin][f] * sum_c part[b][c][bin*64+f]
// Writes EVERY output element -> no d_out memset needed on this path.
__global__ __launch_bounds__(256)
void finalize_kernel(const unsigned* __restrict__ part, float* __restrict__ out,
                     const float* __restrict__ w) {
    int t = blockIdx.x * blockDim.x + threadIdx.x;   // 65536 threads, 4 elems each
    int i = t * 4;                                   // flat index into out
    int b = i >> 13;                                 // / SEG
    int j = i & (SEG - 1);

    const unsigned* pb = part + (size_t)b * CHUNKS * SEG + j;
    uint4 acc = make_uint4(0u, 0u, 0u, 0u);
    for (int c = 0; c < CHUNKS; ++c) {
        uint4 v = *(const uint4*)(pb + (size_t)c * SEG);  // coalesced across lanes
        acc.x += v.x; acc.y += v.y; acc.z += v.z; acc.w += v.w;
    }
    float4 wv = *(const float4*)&w[j];
    float4 o;
    o.x = (float)acc.x * wv.x;
    o.y = (float)acc.y * wv.y;
    o.z = (float)acc.z * wv.z;
    o.w = (float)acc.w * wv.w;
    *(float4*)&out[i] = o;
}

// ---------- fallback path (round-1, proven correct): atomics into d_out ----------

__global__ __launch_bounds__(THREADS, 8)
void hist_atomic_kernel(const float* __restrict__ x, unsigned* out) {
    __shared__ unsigned hist[SEG];
    for (int i = threadIdx.x; i < SEG; i += THREADS) hist[i] = 0u;
    __syncthreads();

    const int c    = blockIdx.x;
    const int b    = blockIdx.y;
    const int lane = threadIdx.x & 63;
    const int wave = threadIdx.x >> 6;

    const float* xb = x + ((size_t)b * S_DIM
                           + (size_t)c * ROWS_PER_BLOCK
                           + wave * ROWS_PER_WAVE) * FEAT;

    for (int it = 0; it < ROWS_PER_WAVE; it += UNROLL) {
        float v[UNROLL];
        #pragma unroll
        for (int u = 0; u < UNROLL; ++u)
            v[u] = xb[(it + u) * FEAT + lane];
        #pragma unroll
        for (int u = 0; u < UNROLL; ++u) {
            int bin = (int)(v[u] * 128.0f);
            bin = bin < 0 ? 0 : (bin > 127 ? 127 : bin);
            atomicAdd(&hist[(bin << 6) + lane], 1u);
        }
    }
    __syncthreads();

    unsigned* gout = out + (size_t)b * SEG;
    for (int i = threadIdx.x; i < SEG; i += THREADS) {
        unsigned cval = hist[i];
        if (cval) atomicAdd(&gout[i], cval);
    }
}

__global__ void finalize_inplace_kernel(const unsigned* cnt, float* out,
                                        const float* __restrict__ w, int n) {
    int i = blockIdx.x * blockDim.x + threadIdx.x;
    if (i < n) {
        unsigned cval = cnt[i];
        out[i] = (float)cval * w[i & (SEG - 1)];
    }
}

extern "C" void kernel_launch(void* const* d_in, const int* in_sizes, int n_in,
                              void* d_out, int out_size, void* d_ws, size_t ws_size,
                              hipStream_t stream) {
    const float* x = (const float*)d_in[0];
    const float* w = (const float*)d_in[1];
    float* out = (float*)d_out;

    const size_t part_bytes = (size_t)B_DIM * CHUNKS * SEG * sizeof(unsigned); // 32 MiB
    dim3 grid(CHUNKS, B_DIM);

    if (ws_size >= part_bytes && d_ws != nullptr) {
        // Main path: private partials, no global atomics, no d_out memset.
        unsigned* part = (unsigned*)d_ws;
        hist_kernel<<<grid, THREADS, 0, stream>>>(x, part);
        int n_vec_threads = (B_DIM * SEG) / 4;       // 65536
        finalize_kernel<<<n_vec_threads / 256, 256, 0, stream>>>(part, out, w);
    } else {
        // Fallback (round-1 proven): zero d_out, atomic merge, in-place finalize.
        hipMemsetAsync(d_out, 0, (size_t)out_size * sizeof(float), stream);
        hist_atomic_kernel<<<grid, THREADS, 0, stream>>>(x, (unsigned*)d_out);
        int n = out_size;
        finalize_inplace_kernel<<<(n + 255) / 256, 256, 0, stream>>>(
            (const unsigned*)d_out, out, w, n);
    }
}